// Round 4
// baseline (748.588 us; speedup 1.0000x reference)
//
#include <hip/hip_runtime.h>
#include <stdint.h>

#define NN 8192
#define K_ORD 262144u      // ordered top-k positions (off-diagonal, both triangles)
#define TIE_CAP 16384u
#define NB 256             // mega-kernel blocks == probes per round
#define NT 512             // threads per block

// ws layout (uint32 words):
// [0..1023]     counts: round r (0..3) writes [r*256 .. r*256+255]
// [1024] r_ord  [1025] tie_cnt
// [1026..1035]  grid barriers: 5 phases x {counter, flag}
// [1040..9231]  sorted p values (8192 floats, desc by key)
// [9232..]      tie flat-indices
#define WS_R 1024
#define WS_TIECNT 1025
#define WS_BAR 1026
#define WS_INIT0 1024
#define WS_INITN 12
#define WS_SORT 1040
#define WS_TIE 9232

__device__ __forceinline__ uint32_t fkey(float x) {
    // order-preserving map float -> uint32 (neg: ~u, pos: u|0x80000000)
    uint32_t u = __float_as_uint(x);
    uint32_t m = (uint32_t)((int32_t)u >> 31) | 0x80000000u;
    return u ^ m;
}
__device__ __forceinline__ float inv_fkey(uint32_t k) {
    uint32_t u = (k & 0x80000000u) ? (k ^ 0x80000000u) : ~k;
    return __uint_as_float(u);
}

__global__ void init_kernel(uint32_t* __restrict__ ws) {
    if (threadIdx.x < WS_INITN) ws[WS_INIT0 + threadIdx.x] = 0u;
}

// Device-scope grid barrier; all NB blocks co-resident (NB=256 <= 1 per CU).
__device__ __forceinline__ void grid_barrier(uint32_t* __restrict__ bar, int phase) {
    __threadfence();
    __syncthreads();
    if (threadIdx.x == 0) {
        const uint32_t old = __hip_atomic_fetch_add(&bar[phase * 2], 1u,
                                                    __ATOMIC_ACQ_REL, __HIP_MEMORY_SCOPE_AGENT);
        if (old == NB - 1) {
            __hip_atomic_store(&bar[phase * 2 + 1], 1u,
                               __ATOMIC_RELEASE, __HIP_MEMORY_SCOPE_AGENT);
        } else {
            while (__hip_atomic_load(&bar[phase * 2 + 1],
                                     __ATOMIC_ACQUIRE, __HIP_MEMORY_SCOPE_AGENT) == 0u)
                __builtin_amdgcn_s_sleep(2);
        }
    }
    __syncthreads();
    __threadfence();
}

// f(T) = #{ordered (a,b), a!=b : fkey(ps[a]*ps[b]) > T}, ps sorted desc by key.
// Per a: predicate is prefix-true (pa>=0) or suffix-true (pa<0): 14-step binary
// search over [0,8192] (first step NN so pos can reach 8192).
__device__ uint32_t eval_count(const float* __restrict__ ps, uint32_t T) {
    const int tx = threadIdx.x;
    uint32_t cnt = 0;
    for (int q = 0; q < NN / NT; ++q) {
        const int a = tx * (NN / NT) + q;
        const float pa = ps[a];
        const uint32_t neg = __float_as_uint(pa) >> 31;
        int pos = 0;
#pragma unroll
        for (int st = NN; st > 0; st >>= 1) {
            const int cand = pos + st;
            if (cand <= NN) {
                const uint32_t kk = fkey(pa * ps[cand - 1]);
                const uint32_t pr = (kk > T) ? 1u : 0u;
                if (pr ^ neg) pos = cand;
            }
        }
        uint32_t c = neg ? (uint32_t)(NN - pos) : (uint32_t)pos;
        c -= (fkey(pa * pa) > T) ? 1u : 0u;   // exclude the diagonal pairing
        cnt += c;
    }
    return cnt;
}

// Recompute bracket after `rounds` completed rounds (invariant: T* in [lo,hi],
// f(hi) < K). Counts read with agent-scope atomic loads (cross-XCD visibility).
__device__ void bracket_chain(const uint32_t* __restrict__ ws, int rounds,
                              uint32_t* __restrict__ sh,
                              uint32_t& lo, uint32_t& hi, uint32_t& fstar) {
    const int tx = threadIdx.x;
    lo = 0u; hi = 0xFFFFFFFFu; fstar = 0u;
    for (int r = 0; r < rounds; ++r) {
        uint32_t flag = 1024u;
        if (tx < 256) {
            const uint32_t c = __hip_atomic_load(&ws[r * 256 + tx],
                                                 __ATOMIC_RELAXED, __HIP_MEMORY_SCOPE_AGENT);
            if (c < K_ORD) flag = (uint32_t)tx;
        }
        sh[tx] = flag;
        __syncthreads();
        for (int off = NT / 2; off > 0; off >>= 1) {
            if (tx < off) sh[tx] = min(sh[tx], sh[tx + off]);
            __syncthreads();
        }
        const uint32_t cs = sh[0];   // minimal c with f(T_c) < K
        __syncthreads();
        fstar = __hip_atomic_load(&ws[r * 256 + cs],
                                  __ATOMIC_RELAXED, __HIP_MEMORY_SCOPE_AGENT);
        const uint64_t W = (uint64_t)(hi - lo);
        const uint32_t Tc = lo + (uint32_t)(((uint64_t)(cs + 1) * W) >> 8);
        if (cs > 0) lo = lo + (uint32_t)(((uint64_t)cs * W) >> 8) + 1u;
        hi = Tc;
    }
}

// ONE kernel: rank-sort -> 4 descent rounds -> local finalize -> 268MB mask.
__global__ void __launch_bounds__(NT) mega_kernel(const float* __restrict__ p,
                                                  float* __restrict__ out,
                                                  uint32_t* __restrict__ ws) {
    __shared__ uint32_t smem[NN + NT];   // [0..NN): keys then sorted ps; [NN..): sh
    uint32_t* sh = smem + NN;
    const int tx = threadIdx.x;
    const int bx = blockIdx.x;

    // ---- phase 0: rank-sort (block ranks 32 elems; 2 elems share each read) ----
    for (int t = tx; t < NN / 4; t += NT) {
        const float4 v = reinterpret_cast<const float4*>(p)[t];
        reinterpret_cast<uint4*>(smem)[t] =
            make_uint4(fkey(v.x), fkey(v.y), fkey(v.z), fkey(v.w));
    }
    __syncthreads();
    {
        const int seg = tx & 31;            // LDS bank-aligned segment
        const int e0 = bx * 32 + (tx >> 5); // tx>>5 in 0..15
        const int e1 = e0 + 16;
        const uint32_t k0 = smem[e0], k1 = smem[e1];
        uint32_t c0 = 0, c1 = 0;
        for (int it = 0; it < 256; ++it) {
            const int j = seg + 32 * it;
            const uint32_t kj = smem[j];
            c0 += (kj > k0) ? 1u : ((kj == k0 && j < e0) ? 1u : 0u);
            c1 += (kj > k1) ? 1u : ((kj == k1 && j < e1) ? 1u : 0u);
        }
        for (int off = 16; off > 0; off >>= 1) {
            c0 += __shfl_down(c0, off, 32);
            c1 += __shfl_down(c1, off, 32);
        }
        if (seg == 0) {
            __hip_atomic_store(&ws[WS_SORT + c0], __float_as_uint(inv_fkey(k0)),
                               __ATOMIC_RELAXED, __HIP_MEMORY_SCOPE_AGENT);
            __hip_atomic_store(&ws[WS_SORT + c1], __float_as_uint(inv_fkey(k1)),
                               __ATOMIC_RELAXED, __HIP_MEMORY_SCOPE_AGENT);
        }
    }
    grid_barrier(ws + WS_BAR, 0);

    // ---- load sorted values into LDS (once; reused all rounds) ----
    for (int t = tx; t < NN; t += NT)
        smem[t] = __hip_atomic_load(&ws[WS_SORT + t],
                                    __ATOMIC_RELAXED, __HIP_MEMORY_SCOPE_AGENT);
    __syncthreads();
    const float* ps = reinterpret_cast<const float*>(smem);

    // ---- phases 1..4: base-256 bracket descent; block bx evaluates probe bx ----
    for (int r = 0; r < 4; ++r) {
        uint32_t lo, hi, fs;
        bracket_chain(ws, r, sh, lo, hi, fs);
        const uint64_t W = (uint64_t)(hi - lo);
        const uint32_t T = lo + (uint32_t)(((uint64_t)(bx + 1) * W) >> 8);
        const uint32_t cnt = eval_count(ps, T);
        __syncthreads();
        sh[tx] = cnt;
        __syncthreads();
        for (int off = 256; off > 0; off >>= 1) {
            if (tx < off) sh[tx] += sh[tx + off];
            __syncthreads();
        }
        if (tx == 0)
            __hip_atomic_store(&ws[r * 256 + bx], sh[0],
                               __ATOMIC_RELAXED, __HIP_MEMORY_SCOPE_AGENT);
        grid_barrier(ws + WS_BAR, r + 1);
    }

    // ---- local finalize: every block recomputes the collapsed bracket ----
    uint32_t lo, hi, fs;
    bracket_chain(ws, 4, sh, lo, hi, fs);
    const uint32_t Tk = hi;              // exact K-th largest key
    if (bx == 0 && tx == 0)
        __hip_atomic_store(&ws[WS_R], K_ORD - fs,
                           __ATOMIC_RELAXED, __HIP_MEMORY_SCOPE_AGENT);

    // ---- mask: grid-stride 268MB write; 1.0 iff key > Tk; ==Tk -> tie buffer ----
    const float4* p4 = reinterpret_cast<const float4*>(p);
    float4* out4 = reinterpret_cast<float4*>(out);
    const uint32_t t0 = (uint32_t)(bx * NT + tx);
    const uint32_t col4 = t0 & 2047u;     // loop-invariant column group
    const float4 pj = p4[col4];
    const float pjv[4] = {pj.x, pj.y, pj.z, pj.w};
    const uint32_t j0 = col4 * 4u;
    for (uint32_t t = t0; t < (uint32_t)(NN / 4) * (uint32_t)NN; t += NB * NT) {
        const uint32_t i = t >> 11;       // 2048 float4 per row
        const float pi = p[i];
        float vv[4];
#pragma unroll
        for (int c = 0; c < 4; ++c) {
            const uint32_t jj = j0 + c;
            float v = 0.0f;
            if (jj != i) {
                const uint32_t key = fkey(pi * pjv[c]);
                if (key > Tk) {
                    v = 1.0f;
                } else if (key == Tk) {
                    const uint32_t pos = atomicAdd(&ws[WS_TIECNT], 1u);
                    if (pos < TIE_CAP)
                        __hip_atomic_store(&ws[WS_TIE + pos], i * NN + jj,
                                           __ATOMIC_RELAXED, __HIP_MEMORY_SCOPE_AGENT);
                }
            }
            vv[c] = v;
        }
        float4 o;
        o.x = vv[0]; o.y = vv[1]; o.z = vv[2]; o.w = vv[3];
        out4[t] = o;
    }
}

// Separate kernel (kernel boundary = clean coherence): among the n (key==Tk)
// entries set the r with smallest flat index to 1.0 — jax.lax.top_k tie rule.
__global__ void __launch_bounds__(256) tie_select_kernel(float* __restrict__ out,
                                                         uint32_t* __restrict__ ws) {
    uint32_t n = ws[WS_TIECNT];
    if (n > TIE_CAP) n = TIE_CAP;
    const uint32_t r = ws[WS_R];
    for (uint32_t e = threadIdx.x; e < n; e += 256) {
        const uint32_t idx = ws[WS_TIE + e];
        uint32_t rank = 0;
        for (uint32_t m = 0; m < n; ++m) rank += (ws[WS_TIE + m] < idx) ? 1u : 0u;
        if (rank < r) out[idx] = 1.0f;
    }
}

extern "C" void kernel_launch(void* const* d_in, const int* in_sizes, int n_in,
                              void* d_out, int out_size, void* d_ws, size_t ws_size,
                              hipStream_t stream) {
    const float* p = (const float*)d_in[0];
    float* out = (float*)d_out;
    uint32_t* ws = (uint32_t*)d_ws;

    init_kernel<<<1, 64, 0, stream>>>(ws);
    mega_kernel<<<NB, NT, 0, stream>>>(p, out, ws);
    tie_select_kernel<<<1, 256, 0, stream>>>(out, ws);
}

// Round 6
// 472.263 us; speedup vs baseline: 1.5851x; 1.5851x over previous
//
#include <hip/hip_runtime.h>
#include <stdint.h>

#define NN 8192
#define K_ORD 262144u      // ordered top-k positions (off-diagonal, both triangles)
#define TIE_CAP 16384u

typedef float vfloat4 __attribute__((ext_vector_type(4)));  // clang-native for nontemporal

// ws layout (uint32 words):
// [0..1023]    counts: round r (1..4) accumulates in [(r-1)*256 .. +255]
// [1024] Tk  [1025] above  [1026] r_ord  [1027] tie_cnt  [1028] done_ctr
// [1032..9223] sorted p values (8192 floats, desc by key)
// [9224..]     tie flat-indices
#define WS_TK 1024
#define WS_ABOVE 1025
#define WS_R 1026
#define WS_TIECNT 1027
#define WS_DONE 1028
#define WS_SORT 1032
#define WS_TIE 9224
#define WS_ZERO 1032       // words zeroed by sort block 0

__device__ __forceinline__ uint32_t fkey(float x) {
    // order-preserving map float -> uint32 (neg: ~u, pos: u|0x80000000)
    uint32_t u = __float_as_uint(x);
    uint32_t m = (uint32_t)((int32_t)u >> 31) | 0x80000000u;
    return u ^ m;
}
__device__ __forceinline__ float inv_fkey(uint32_t k) {
    uint32_t u = (k & 0x80000000u) ? (k ^ 0x80000000u) : ~k;
    return __uint_as_float(u);
}

// ---------------------------------------------------------------------------
// Kernel 1: brute-force rank sort of p (desc by key, ties by index) -> ws sorted.
// 1024 blocks x 256 thr; block ranks 8 elements; thread = (elem, 32-seg).
// Block 0 also zeroes the counts/state words (they feed later atomicAdds).
__global__ void __launch_bounds__(256) sort_kernel(const float* __restrict__ p,
                                                   uint32_t* __restrict__ ws) {
    __shared__ uint32_t ks[NN];
    const int tx = threadIdx.x;
    if (blockIdx.x == 0)
        for (int t = tx; t < WS_ZERO; t += 256) ws[t] = 0u;
    for (int t = tx; t < NN / 4; t += 256) {
        const float4 v = reinterpret_cast<const float4*>(p)[t];
        reinterpret_cast<uint4*>(ks)[t] =
            make_uint4(fkey(v.x), fkey(v.y), fkey(v.z), fkey(v.w));
    }
    __syncthreads();
    const int e = blockIdx.x * 8 + (tx >> 5);
    const int seg = tx & 31;
    const uint32_t ke = ks[e];
    uint32_t cnt = 0;
    for (int it = 0; it < 256; ++it) {
        const int j = seg + 32 * it;
        const uint32_t kj = ks[j];
        cnt += (kj > ke) ? 1u : 0u;
        cnt += (kj == ke && j < e) ? 1u : 0u;
    }
    for (int off = 16; off > 0; off >>= 1) cnt += __shfl_down(cnt, off, 32);
    if (seg == 0)
        reinterpret_cast<float*>(ws + WS_SORT)[cnt] = inv_fkey(ke);  // unique rank
}

// ---------------------------------------------------------------------------
// Partial f(T) over rows [a0, a0+2048): 4 searches per thread, run as 4
// INDEPENDENT interleaved chains (4 LDS loads in flight per step -> ~4x less
// latency-bound than serial searches). Search space [0,8192], 14 steps.
__device__ uint32_t eval_count4(const float* __restrict__ ps, uint32_t T, int a0) {
    const int a = a0 + threadIdx.x * 4;
    float pa[4];
    uint32_t neg[4];
    int pos[4] = {0, 0, 0, 0};
#pragma unroll
    for (int c = 0; c < 4; ++c) {
        pa[c] = ps[a + c];
        neg[c] = __float_as_uint(pa[c]) >> 31;
    }
#pragma unroll
    for (int st = NN; st > 0; st >>= 1) {
#pragma unroll
        for (int c = 0; c < 4; ++c) {
            const int cand = pos[c] + st;
            if (cand <= NN) {
                const uint32_t pr = (fkey(pa[c] * ps[cand - 1]) > T) ? 1u : 0u;
                if (pr ^ neg[c]) pos[c] = cand;
            }
        }
    }
    uint32_t cnt = 0;
#pragma unroll
    for (int c = 0; c < 4; ++c) {
        uint32_t cc = neg[c] ? (uint32_t)(NN - pos[c]) : (uint32_t)pos[c];
        cc -= (fkey(pa[c] * pa[c]) > T) ? 1u : 0u;   // exclude diagonal pairing
        cnt += cc;
    }
    return cnt;
}

// Recompute bracket after `rounds` completed rounds. Invariant: T* (minimal T
// with f(T) < K) in [lo,hi], f(hi) < K. Deterministic; identical arithmetic
// everywhere it is called.
__device__ void bracket_chain(const uint32_t* __restrict__ ws, int rounds,
                              uint32_t* __restrict__ sh,
                              uint32_t& lo, uint32_t& hi, uint32_t& fstar) {
    const int tx = threadIdx.x;
    lo = 0u; hi = 0xFFFFFFFFu; fstar = 0u;
    for (int r = 0; r < rounds; ++r) {
        uint32_t flag = 1024u;
        if (tx < 256) {
            const uint32_t c = __hip_atomic_load(&ws[r * 256 + tx],
                                                 __ATOMIC_RELAXED, __HIP_MEMORY_SCOPE_AGENT);
            if (c < K_ORD) flag = (uint32_t)tx;
        }
        sh[tx] = flag;
        __syncthreads();
        for (int off = 256; off > 0; off >>= 1) {
            if (tx < off) sh[tx] = min(sh[tx], sh[tx + off]);
            __syncthreads();
        }
        const uint32_t cs = sh[0];   // minimal c with f(T_c) < K (exists: f(hi)<K)
        __syncthreads();
        fstar = __hip_atomic_load(&ws[r * 256 + cs],
                                  __ATOMIC_RELAXED, __HIP_MEMORY_SCOPE_AGENT);
        const uint64_t W = (uint64_t)(hi - lo);
        const uint32_t Tc = lo + (uint32_t)(((uint64_t)(cs + 1) * W) >> 8);
        if (cs > 0) lo = lo + (uint32_t)(((uint64_t)cs * W) >> 8) + 1u;
        hi = Tc;
    }
}

// Kernels 2-5: one descent round. 1024 blocks: block = (probe = bx>>2,
// quarter = bx&3); partial counts accumulate via device atomicAdd.
// ROUND 4 additionally finalizes via last-block election (R1-proven pattern).
template <int ROUND>
__global__ void __launch_bounds__(512) select_round_kernel(uint32_t* __restrict__ ws) {
    __shared__ float ps[NN];
    __shared__ uint32_t sh[512];
    __shared__ uint32_t lastf;
    const int tx = threadIdx.x;
    const int probe = blockIdx.x >> 2;
    const int quarter = blockIdx.x & 3;
    for (int t = tx; t < NN / 4; t += 512)
        reinterpret_cast<float4*>(ps)[t] =
            reinterpret_cast<const float4*>(ws + WS_SORT)[t];
    __syncthreads();
    uint32_t lo, hi, fs;
    bracket_chain(ws, ROUND - 1, sh, lo, hi, fs);
    const uint64_t W = (uint64_t)(hi - lo);
    const uint32_t T = lo + (uint32_t)(((uint64_t)(probe + 1) * W) >> 8);
    const uint32_t cnt = eval_count4(ps, T, quarter * 2048);
    __syncthreads();
    sh[tx] = cnt;
    __syncthreads();
    for (int off = 256; off > 0; off >>= 1) {
        if (tx < off) sh[tx] += sh[tx + off];
        __syncthreads();
    }
    if (tx == 0) atomicAdd(&ws[(ROUND - 1) * 256 + probe], sh[0]);

    if (ROUND == 4) {
        __threadfence();
        __syncthreads();
        if (tx == 0) {
            const uint32_t old = __hip_atomic_fetch_add(&ws[WS_DONE], 1u,
                                                        __ATOMIC_ACQ_REL, __HIP_MEMORY_SCOPE_AGENT);
            lastf = (old == 1023u) ? 1u : 0u;
        }
        __syncthreads();
        if (lastf) {   // last-finishing block: all round-4 counts are visible
            bracket_chain(ws, 4, sh, lo, hi, fs);
            if (tx == 0) {
                ws[WS_TK] = hi;           // bracket collapsed: exact K-th key
                ws[WS_R] = K_ORD - fs;    // in-class slots, filled by index asc
            }
        }
    }
}

// Kernel 6: streamed 268MB mask write (nontemporal: out is never re-read).
// 1.0 iff key > Tk; key == Tk -> tie buffer.
__global__ void __launch_bounds__(256) mask_kernel(const float* __restrict__ p,
                                                   float* __restrict__ out,
                                                   uint32_t* __restrict__ ws) {
    const int tx = threadIdx.x;
    const int i = blockIdx.y;
    const int jb0 = blockIdx.x * 4096;
    const uint32_t Tk = ws[WS_TK];
    const float pi = p[i];
    const size_t rowbase = (size_t)i * NN;
#pragma unroll
    for (int q = 0; q < 4; ++q) {
        const int j = jb0 + q * 1024 + tx * 4;
        const float4 pj = *reinterpret_cast<const float4*>(p + j);
        const float pjv[4] = {pj.x, pj.y, pj.z, pj.w};
        float vv[4];
#pragma unroll
        for (int c = 0; c < 4; ++c) {
            const int jj = j + c;
            float v = 0.0f;
            if (jj != i) {
                const uint32_t key = fkey(pi * pjv[c]);
                if (key > Tk) {
                    v = 1.0f;
                } else if (key == Tk) {
                    const uint32_t pos = atomicAdd(&ws[WS_TIECNT], 1u);
                    if (pos < TIE_CAP) ws[WS_TIE + pos] = (uint32_t)(i * NN + jj);
                }
            }
            vv[c] = v;
        }
        vfloat4 o = {vv[0], vv[1], vv[2], vv[3]};
        __builtin_nontemporal_store(o, reinterpret_cast<vfloat4*>(out + rowbase + j));
    }
}

// Kernel 7: among the n (key == Tk) entries set the r with smallest flat index
// to 1.0 — exactly jax.lax.top_k's tie rule. n is tiny (usually 2).
__global__ void __launch_bounds__(256) tie_select_kernel(float* __restrict__ out,
                                                         uint32_t* __restrict__ ws) {
    uint32_t n = ws[WS_TIECNT];
    if (n > TIE_CAP) n = TIE_CAP;
    const uint32_t r = ws[WS_R];
    for (uint32_t e = threadIdx.x; e < n; e += 256) {
        const uint32_t idx = ws[WS_TIE + e];
        uint32_t rank = 0;
        for (uint32_t m = 0; m < n; ++m) rank += (ws[WS_TIE + m] < idx) ? 1u : 0u;
        if (rank < r) out[idx] = 1.0f;
    }
}

extern "C" void kernel_launch(void* const* d_in, const int* in_sizes, int n_in,
                              void* d_out, int out_size, void* d_ws, size_t ws_size,
                              hipStream_t stream) {
    const float* p = (const float*)d_in[0];
    float* out = (float*)d_out;
    uint32_t* ws = (uint32_t*)d_ws;

    sort_kernel<<<1024, 256, 0, stream>>>(p, ws);
    select_round_kernel<1><<<1024, 512, 0, stream>>>(ws);
    select_round_kernel<2><<<1024, 512, 0, stream>>>(ws);
    select_round_kernel<3><<<1024, 512, 0, stream>>>(ws);
    select_round_kernel<4><<<1024, 512, 0, stream>>>(ws);
    mask_kernel<<<dim3(2, NN), 256, 0, stream>>>(p, out, ws);
    tie_select_kernel<<<1, 256, 0, stream>>>(out, ws);
}

// Round 7
// 463.060 us; speedup vs baseline: 1.6166x; 1.0199x over previous
//
#include <hip/hip_runtime.h>
#include <stdint.h>

#define NN 8192
#define K_ORD 262144u      // ordered top-k positions (off-diagonal, both triangles)
#define TIE_CAP 16384u

// ws layout (uint32 words):
// [0..1023]    counts: round r (1..4) accumulates in [(r-1)*256 .. +255]
// [1024] Tk  [1025] above  [1026] r_ord  [1027] tie_cnt  [1028] done_ctr
// [1032..9223] sorted p values (8192 floats, desc by key)
// [9224..]     tie flat-indices
#define WS_TK 1024
#define WS_ABOVE 1025
#define WS_R 1026
#define WS_TIECNT 1027
#define WS_DONE 1028
#define WS_SORT 1032
#define WS_TIE 9224
#define WS_ZERO 1032       // words zeroed by sort block 0

__device__ __forceinline__ uint32_t fkey(float x) {
    // order-preserving map float -> uint32 (neg: ~u, pos: u|0x80000000)
    uint32_t u = __float_as_uint(x);
    uint32_t m = (uint32_t)((int32_t)u >> 31) | 0x80000000u;
    return u ^ m;
}
__device__ __forceinline__ float inv_fkey(uint32_t k) {
    uint32_t u = (k & 0x80000000u) ? (k ^ 0x80000000u) : ~k;
    return __uint_as_float(u);
}

// ---------------------------------------------------------------------------
// Kernel 1: brute-force rank sort of p (desc by key, ties by index) -> ws sorted.
// 1024 blocks x 256 thr; block ranks 8 elements; thread = (elem, 32-seg).
// Block 0 also zeroes the counts/state words (they feed later atomicAdds).
__global__ void __launch_bounds__(256) sort_kernel(const float* __restrict__ p,
                                                   uint32_t* __restrict__ ws) {
    __shared__ uint32_t ks[NN];
    const int tx = threadIdx.x;
    if (blockIdx.x == 0)
        for (int t = tx; t < WS_ZERO; t += 256) ws[t] = 0u;
    for (int t = tx; t < NN / 4; t += 256) {
        const float4 v = reinterpret_cast<const float4*>(p)[t];
        reinterpret_cast<uint4*>(ks)[t] =
            make_uint4(fkey(v.x), fkey(v.y), fkey(v.z), fkey(v.w));
    }
    __syncthreads();
    const int e = blockIdx.x * 8 + (tx >> 5);
    const int seg = tx & 31;
    const uint32_t ke = ks[e];
    uint32_t cnt = 0;
    for (int it = 0; it < 256; ++it) {
        const int j = seg + 32 * it;
        const uint32_t kj = ks[j];
        cnt += (kj > ke) ? 1u : 0u;
        cnt += (kj == ke && j < e) ? 1u : 0u;
    }
    for (int off = 16; off > 0; off >>= 1) cnt += __shfl_down(cnt, off, 32);
    if (seg == 0)
        reinterpret_cast<float*>(ws + WS_SORT)[cnt] = inv_fkey(ke);  // unique rank
}

// ---------------------------------------------------------------------------
// Partial f(T) over rows [a0, a0+2048): 4 searches per thread, run as 4
// INDEPENDENT interleaved chains (4 LDS loads in flight per step -> ~4x less
// latency-bound than serial searches). Search space [0,8192], 14 steps.
__device__ uint32_t eval_count4(const float* __restrict__ ps, uint32_t T, int a0) {
    const int a = a0 + threadIdx.x * 4;
    float pa[4];
    uint32_t neg[4];
    int pos[4] = {0, 0, 0, 0};
#pragma unroll
    for (int c = 0; c < 4; ++c) {
        pa[c] = ps[a + c];
        neg[c] = __float_as_uint(pa[c]) >> 31;
    }
#pragma unroll
    for (int st = NN; st > 0; st >>= 1) {
#pragma unroll
        for (int c = 0; c < 4; ++c) {
            const int cand = pos[c] + st;
            if (cand <= NN) {
                const uint32_t pr = (fkey(pa[c] * ps[cand - 1]) > T) ? 1u : 0u;
                if (pr ^ neg[c]) pos[c] = cand;
            }
        }
    }
    uint32_t cnt = 0;
#pragma unroll
    for (int c = 0; c < 4; ++c) {
        uint32_t cc = neg[c] ? (uint32_t)(NN - pos[c]) : (uint32_t)pos[c];
        cc -= (fkey(pa[c] * pa[c]) > T) ? 1u : 0u;   // exclude diagonal pairing
        cnt += cc;
    }
    return cnt;
}

// Recompute bracket after `rounds` completed rounds. Invariant: T* (minimal T
// with f(T) < K) in [lo,hi], f(hi) < K. Deterministic; identical arithmetic
// everywhere it is called.
__device__ void bracket_chain(const uint32_t* __restrict__ ws, int rounds,
                              uint32_t* __restrict__ sh,
                              uint32_t& lo, uint32_t& hi, uint32_t& fstar) {
    const int tx = threadIdx.x;
    lo = 0u; hi = 0xFFFFFFFFu; fstar = 0u;
    for (int r = 0; r < rounds; ++r) {
        uint32_t flag = 1024u;
        if (tx < 256) {
            const uint32_t c = __hip_atomic_load(&ws[r * 256 + tx],
                                                 __ATOMIC_RELAXED, __HIP_MEMORY_SCOPE_AGENT);
            if (c < K_ORD) flag = (uint32_t)tx;
        }
        sh[tx] = flag;
        __syncthreads();
        for (int off = 256; off > 0; off >>= 1) {
            if (tx < off) sh[tx] = min(sh[tx], sh[tx + off]);
            __syncthreads();
        }
        const uint32_t cs = sh[0];   // minimal c with f(T_c) < K (exists: f(hi)<K)
        __syncthreads();
        fstar = __hip_atomic_load(&ws[r * 256 + cs],
                                  __ATOMIC_RELAXED, __HIP_MEMORY_SCOPE_AGENT);
        const uint64_t W = (uint64_t)(hi - lo);
        const uint32_t Tc = lo + (uint32_t)(((uint64_t)(cs + 1) * W) >> 8);
        if (cs > 0) lo = lo + (uint32_t)(((uint64_t)cs * W) >> 8) + 1u;
        hi = Tc;
    }
}

// Kernels 2-5: one descent round. 1024 blocks: block = (probe = bx>>2,
// quarter = bx&3); partial counts accumulate via device atomicAdd.
// ROUND 4 additionally finalizes via last-block election (R1-proven pattern).
template <int ROUND>
__global__ void __launch_bounds__(512) select_round_kernel(uint32_t* __restrict__ ws) {
    __shared__ float ps[NN];
    __shared__ uint32_t sh[512];
    __shared__ uint32_t lastf;
    const int tx = threadIdx.x;
    const int probe = blockIdx.x >> 2;
    const int quarter = blockIdx.x & 3;
    for (int t = tx; t < NN / 4; t += 512)
        reinterpret_cast<float4*>(ps)[t] =
            reinterpret_cast<const float4*>(ws + WS_SORT)[t];
    __syncthreads();
    uint32_t lo, hi, fs;
    bracket_chain(ws, ROUND - 1, sh, lo, hi, fs);
    const uint64_t W = (uint64_t)(hi - lo);
    const uint32_t T = lo + (uint32_t)(((uint64_t)(probe + 1) * W) >> 8);
    const uint32_t cnt = eval_count4(ps, T, quarter * 2048);
    __syncthreads();
    sh[tx] = cnt;
    __syncthreads();
    for (int off = 256; off > 0; off >>= 1) {
        if (tx < off) sh[tx] += sh[tx + off];
        __syncthreads();
    }
    if (tx == 0) atomicAdd(&ws[(ROUND - 1) * 256 + probe], sh[0]);

    if (ROUND == 4) {
        __threadfence();
        __syncthreads();
        if (tx == 0) {
            const uint32_t old = __hip_atomic_fetch_add(&ws[WS_DONE], 1u,
                                                        __ATOMIC_ACQ_REL, __HIP_MEMORY_SCOPE_AGENT);
            lastf = (old == 1023u) ? 1u : 0u;
        }
        __syncthreads();
        if (lastf) {   // last-finishing block: all round-4 counts are visible
            bracket_chain(ws, 4, sh, lo, hi, fs);
            if (tx == 0) {
                ws[WS_TK] = hi;           // bracket collapsed: exact K-th key
                ws[WS_R] = K_ORD - fs;    // in-class slots, filled by index asc
            }
        }
    }
}

// Kernel 6: streamed 268MB mask write (plain float4 stores — NT regressed R6).
// 1.0 iff key > Tk; key == Tk -> tie buffer.
__global__ void __launch_bounds__(256) mask_kernel(const float* __restrict__ p,
                                                   float* __restrict__ out,
                                                   uint32_t* __restrict__ ws) {
    const int tx = threadIdx.x;
    const int i = blockIdx.y;
    const int jb0 = blockIdx.x * 4096;
    const uint32_t Tk = ws[WS_TK];
    const float pi = p[i];
    const size_t rowbase = (size_t)i * NN;
#pragma unroll
    for (int q = 0; q < 4; ++q) {
        const int j = jb0 + q * 1024 + tx * 4;
        const float4 pj = *reinterpret_cast<const float4*>(p + j);
        const float pjv[4] = {pj.x, pj.y, pj.z, pj.w};
        float vv[4];
#pragma unroll
        for (int c = 0; c < 4; ++c) {
            const int jj = j + c;
            float v = 0.0f;
            if (jj != i) {
                const uint32_t key = fkey(pi * pjv[c]);
                if (key > Tk) {
                    v = 1.0f;
                } else if (key == Tk) {
                    const uint32_t pos = atomicAdd(&ws[WS_TIECNT], 1u);
                    if (pos < TIE_CAP) ws[WS_TIE + pos] = (uint32_t)(i * NN + jj);
                }
            }
            vv[c] = v;
        }
        float4 o;
        o.x = vv[0]; o.y = vv[1]; o.z = vv[2]; o.w = vv[3];
        *reinterpret_cast<float4*>(out + rowbase + j) = o;
    }
}

// Kernel 7: among the n (key == Tk) entries set the r with smallest flat index
// to 1.0 — exactly jax.lax.top_k's tie rule. n is tiny (usually 2).
__global__ void __launch_bounds__(256) tie_select_kernel(float* __restrict__ out,
                                                         uint32_t* __restrict__ ws) {
    uint32_t n = ws[WS_TIECNT];
    if (n > TIE_CAP) n = TIE_CAP;
    const uint32_t r = ws[WS_R];
    for (uint32_t e = threadIdx.x; e < n; e += 256) {
        const uint32_t idx = ws[WS_TIE + e];
        uint32_t rank = 0;
        for (uint32_t m = 0; m < n; ++m) rank += (ws[WS_TIE + m] < idx) ? 1u : 0u;
        if (rank < r) out[idx] = 1.0f;
    }
}

extern "C" void kernel_launch(void* const* d_in, const int* in_sizes, int n_in,
                              void* d_out, int out_size, void* d_ws, size_t ws_size,
                              hipStream_t stream) {
    const float* p = (const float*)d_in[0];
    float* out = (float*)d_out;
    uint32_t* ws = (uint32_t*)d_ws;

    sort_kernel<<<1024, 256, 0, stream>>>(p, ws);
    select_round_kernel<1><<<1024, 512, 0, stream>>>(ws);
    select_round_kernel<2><<<1024, 512, 0, stream>>>(ws);
    select_round_kernel<3><<<1024, 512, 0, stream>>>(ws);
    select_round_kernel<4><<<1024, 512, 0, stream>>>(ws);
    mask_kernel<<<dim3(2, NN), 256, 0, stream>>>(p, out, ws);
    tie_select_kernel<<<1, 256, 0, stream>>>(out, ws);
}

// Round 8
// 345.912 us; speedup vs baseline: 2.1641x; 1.3387x over previous
//
#include <hip/hip_runtime.h>
#include <stdint.h>

#define NN 8192
#define K_ORD 262144u      // ordered top-k positions (off-diagonal, both triangles)
#define TIE_CAP 16384u

// ws layout (uint32 words):
// [0..4095]    partial counts: round r (1..4) block bx writes [(r-1)*1024 + bx]
//              (bx = probe*4 + quarter; per-probe count = sum of its 4 slots)
// [4096] Tk  [4097] above  [4098] r_ord  [4099] tie_cnt  [4100..4103] pad
// [4104..12295] sorted p values (8192 floats, desc by key)
// [12296..]    tie flat-indices
#define WS_TK 4096
#define WS_R 4098
#define WS_TIECNT 4099
#define WS_STATE0 4096
#define WS_STATEN 8
#define WS_SORT 4104
#define WS_TIE 12296

__device__ __forceinline__ uint32_t fkey(float x) {
    // order-preserving map float -> uint32 (neg: ~u, pos: u|0x80000000)
    uint32_t u = __float_as_uint(x);
    uint32_t m = (uint32_t)((int32_t)u >> 31) | 0x80000000u;
    return u ^ m;
}
__device__ __forceinline__ float inv_fkey(uint32_t k) {
    uint32_t u = (k & 0x80000000u) ? (k ^ 0x80000000u) : ~k;
    return __uint_as_float(u);
}

// ---------------------------------------------------------------------------
// Kernel 1 (R3-verbatim): brute-force rank sort of p (desc by key, ties by
// index) -> ws sorted. 1024 blocks x 256 thr; block ranks 8 elements.
// Block 0 zeroes the 8 state words (counts use plain stores -> no zero needed).
__global__ void __launch_bounds__(256) sort_kernel(const float* __restrict__ p,
                                                   uint32_t* __restrict__ ws) {
    __shared__ uint32_t ks[NN];
    const int tx = threadIdx.x;
    if (blockIdx.x == 0 && tx < WS_STATEN) ws[WS_STATE0 + tx] = 0u;
    for (int t = tx; t < NN / 4; t += 256) {
        const float4 v = reinterpret_cast<const float4*>(p)[t];
        reinterpret_cast<uint4*>(ks)[t] =
            make_uint4(fkey(v.x), fkey(v.y), fkey(v.z), fkey(v.w));
    }
    __syncthreads();
    const int e = blockIdx.x * 8 + (tx >> 5);
    const int seg = tx & 31;
    const uint32_t ke = ks[e];
    uint32_t cnt = 0;
    for (int it = 0; it < 256; ++it) {
        const int j = seg + 32 * it;
        const uint32_t kj = ks[j];
        cnt += (kj > ke) ? 1u : 0u;
        cnt += (kj == ke && j < e) ? 1u : 0u;
    }
    for (int off = 16; off > 0; off >>= 1) cnt += __shfl_down(cnt, off, 32);
    if (seg == 0)
        reinterpret_cast<float*>(ws + WS_SORT)[cnt] = inv_fkey(ke);  // unique rank
}

// ---------------------------------------------------------------------------
// Partial f(T) over rows [a0, a0+2048): R3's proven serial search form, 4 rows
// per thread. Search space [0,8192], 14 steps (first step NN).
__device__ uint32_t eval_count(const float* __restrict__ ps, uint32_t T, int a0) {
    const int tx = threadIdx.x;
    uint32_t cnt = 0;
    for (int q = 0; q < 4; ++q) {
        const int a = a0 + tx * 4 + q;
        const float pa = ps[a];
        const uint32_t neg = __float_as_uint(pa) >> 31;
        int pos = 0;
#pragma unroll
        for (int st = NN; st > 0; st >>= 1) {
            const int cand = pos + st;
            if (cand <= NN) {
                const uint32_t pr = (fkey(pa * ps[cand - 1]) > T) ? 1u : 0u;
                if (pr ^ neg) pos = cand;
            }
        }
        uint32_t c = neg ? (uint32_t)(NN - pos) : (uint32_t)pos;
        c -= (fkey(pa * pa) > T) ? 1u : 0u;   // exclude diagonal pairing
        cnt += c;
    }
    return cnt;
}

// Recompute bracket after `rounds` completed rounds. Per-probe count = sum of
// its 4 partial slots (plain-stored by the 4 quarter-blocks; kernel boundary
// orders them; agent-scope atomic loads for cross-XCD visibility).
template <int NT>
__device__ void bracket_chain(const uint32_t* __restrict__ ws, int rounds,
                              uint32_t* __restrict__ sh,
                              uint32_t& lo, uint32_t& hi, uint32_t& fstar) {
    const int tx = threadIdx.x;
    lo = 0u; hi = 0xFFFFFFFFu; fstar = 0u;
    for (int r = 0; r < rounds; ++r) {
        uint32_t flag = 1024u;
        if (tx < 256) {
            uint32_t c = 0;
#pragma unroll
            for (int q = 0; q < 4; ++q)
                c += __hip_atomic_load(&ws[r * 1024 + tx * 4 + q],
                                       __ATOMIC_RELAXED, __HIP_MEMORY_SCOPE_AGENT);
            if (c < K_ORD) flag = (uint32_t)tx;
        }
        sh[tx] = flag;
        __syncthreads();
        for (int off = NT / 2; off > 0; off >>= 1) {
            if (tx < off) sh[tx] = min(sh[tx], sh[tx + off]);
            __syncthreads();
        }
        const uint32_t cs = sh[0];   // minimal c with f(T_c) < K (exists: f(hi)<K)
        __syncthreads();
        uint32_t fsum = 0;
#pragma unroll
        for (int q = 0; q < 4; ++q)
            fsum += __hip_atomic_load(&ws[r * 1024 + cs * 4 + q],
                                      __ATOMIC_RELAXED, __HIP_MEMORY_SCOPE_AGENT);
        fstar = fsum;
        const uint64_t W = (uint64_t)(hi - lo);
        const uint32_t Tc = lo + (uint32_t)(((uint64_t)(cs + 1) * W) >> 8);
        if (cs > 0) lo = lo + (uint32_t)(((uint64_t)cs * W) >> 8) + 1u;
        hi = Tc;
    }
}

// Kernels 2-5: one descent round. 1024 blocks = (probe = bx>>2, quarter = bx&3).
// Each block PLAIN-STORES its partial count into its own slot — no atomics,
// no election, no threadfence (R3's memory/sync pattern, 4x the parallelism).
template <int ROUND>
__global__ void __launch_bounds__(512) select_round_kernel(uint32_t* __restrict__ ws) {
    __shared__ float ps[NN];
    __shared__ uint32_t sh[512];
    const int tx = threadIdx.x;
    const int bx = blockIdx.x;
    for (int t = tx; t < NN / 4; t += 512)
        reinterpret_cast<float4*>(ps)[t] =
            reinterpret_cast<const float4*>(ws + WS_SORT)[t];
    __syncthreads();
    uint32_t lo, hi, fs;
    bracket_chain<512>(ws, ROUND - 1, sh, lo, hi, fs);
    const uint64_t W = (uint64_t)(hi - lo);
    const uint32_t T = lo + (uint32_t)(((uint64_t)((bx >> 2) + 1) * W) >> 8);
    const uint32_t cnt = eval_count(ps, T, (bx & 3) * 2048);
    __syncthreads();
    sh[tx] = cnt;
    __syncthreads();
    for (int off = 256; off > 0; off >>= 1) {
        if (tx < off) sh[tx] += sh[tx + off];
        __syncthreads();
    }
    if (tx == 0) ws[(ROUND - 1) * 1024 + bx] = sh[0];   // private slot, plain store
}

// Kernel 6 (R3-style separate finalize): after 4 rounds the bracket is a
// single key. Publish Tk and r.
__global__ void __launch_bounds__(256) finalize_kernel(uint32_t* __restrict__ ws) {
    __shared__ uint32_t sh[256];
    uint32_t lo, hi, fs;
    bracket_chain<256>(ws, 4, sh, lo, hi, fs);
    if (threadIdx.x == 0) {
        ws[WS_TK] = hi;               // == lo == exact K-th largest key
        ws[WS_R] = K_ORD - fs;        // in-class slots, filled by index asc
    }
}

// Kernel 7 (R3-verbatim): streamed 268MB mask write, plain float4 stores.
// 1.0 iff key > Tk; key == Tk -> tie buffer.
__global__ void __launch_bounds__(256) mask_kernel(const float* __restrict__ p,
                                                   float* __restrict__ out,
                                                   uint32_t* __restrict__ ws) {
    const int tx = threadIdx.x;
    const int i = blockIdx.y;
    const int jb0 = blockIdx.x * 4096;
    const uint32_t Tk = ws[WS_TK];
    const float pi = p[i];
    const size_t rowbase = (size_t)i * NN;
#pragma unroll
    for (int q = 0; q < 4; ++q) {
        const int j = jb0 + q * 1024 + tx * 4;
        const float4 pj = *reinterpret_cast<const float4*>(p + j);
        const float pjv[4] = {pj.x, pj.y, pj.z, pj.w};
        float vv[4];
#pragma unroll
        for (int c = 0; c < 4; ++c) {
            const int jj = j + c;
            float v = 0.0f;
            if (jj != i) {
                const uint32_t key = fkey(pi * pjv[c]);
                if (key > Tk) {
                    v = 1.0f;
                } else if (key == Tk) {
                    const uint32_t pos = atomicAdd(&ws[WS_TIECNT], 1u);
                    if (pos < TIE_CAP) ws[WS_TIE + pos] = (uint32_t)(i * NN + jj);
                }
            }
            vv[c] = v;
        }
        float4 o;
        o.x = vv[0]; o.y = vv[1]; o.z = vv[2]; o.w = vv[3];
        *reinterpret_cast<float4*>(out + rowbase + j) = o;
    }
}

// Kernel 8 (R3-verbatim): among the n (key == Tk) entries set the r with
// smallest flat index to 1.0 — exactly jax.lax.top_k's tie rule.
__global__ void __launch_bounds__(256) tie_select_kernel(float* __restrict__ out,
                                                         uint32_t* __restrict__ ws) {
    uint32_t n = ws[WS_TIECNT];
    if (n > TIE_CAP) n = TIE_CAP;
    const uint32_t r = ws[WS_R];
    for (uint32_t e = threadIdx.x; e < n; e += 256) {
        const uint32_t idx = ws[WS_TIE + e];
        uint32_t rank = 0;
        for (uint32_t m = 0; m < n; ++m) rank += (ws[WS_TIE + m] < idx) ? 1u : 0u;
        if (rank < r) out[idx] = 1.0f;
    }
}

extern "C" void kernel_launch(void* const* d_in, const int* in_sizes, int n_in,
                              void* d_out, int out_size, void* d_ws, size_t ws_size,
                              hipStream_t stream) {
    const float* p = (const float*)d_in[0];
    float* out = (float*)d_out;
    uint32_t* ws = (uint32_t*)d_ws;

    sort_kernel<<<1024, 256, 0, stream>>>(p, ws);
    select_round_kernel<1><<<1024, 512, 0, stream>>>(ws);
    select_round_kernel<2><<<1024, 512, 0, stream>>>(ws);
    select_round_kernel<3><<<1024, 512, 0, stream>>>(ws);
    select_round_kernel<4><<<1024, 512, 0, stream>>>(ws);
    finalize_kernel<<<1, 256, 0, stream>>>(ws);
    mask_kernel<<<dim3(2, NN), 256, 0, stream>>>(p, out, ws);
    tie_select_kernel<<<1, 256, 0, stream>>>(out, ws);
}